// Round 5
// baseline (108.334 us; speedup 1.0000x reference)
//
#include <hip/hip_runtime.h>
#include <math.h>

#define EPS_F 1e-8f

__device__ __forceinline__ float frcp(float x) { return __builtin_amdgcn_rcpf(x); }

__global__ void __launch_bounds__(64) iou3d_init(double* acc) {
    if (threadIdx.x == 0) { acc[0] = 0.0; acc[1] = 0.0; }
}

__global__ void __launch_bounds__(256, 4) iou3d_main(
    const float* __restrict__ pred_iou,
    const float* __restrict__ pred_boxes,   // N x 7: x y z w l h yaw
    const float* __restrict__ gt_boxes,     // N x 8: x y z w l h sin cos
    const int*   __restrict__ mask,
    double* __restrict__ acc,
    int N)
{
    int i = blockIdx.x * blockDim.x + threadIdx.x;
    float wabs = 0.f, mval = 0.f;

    if (i < N) {
        const float* b1 = pred_boxes + (size_t)i * 7;
        const float* b2 = gt_boxes   + (size_t)i * 8;
        float m = (float)mask[i];
        mval = m;

        float x1c = b1[0], y1c = b1[1], w1 = b1[3], h1 = b1[4], a1 = b1[6];
        float x2c = b2[0], y2c = b2[1], w2 = b2[3], h2 = b2[4];
        float s2v = b2[6], c2v = b2[7];

        // cos/sin of gt yaw without atan2: cos(atan2(s,c)) = c/sqrt(s^2+c^2)
        float invn = rsqrtf(s2v * s2v + c2v * c2v);
        float cs2 = c2v * invn, sn2 = s2v * invn;
        // pred yaw in [-pi,pi]: raw v_sin/v_cos (input in revolutions)
        const float INV2PI = 0.15915494309189535f;
        float sn1 = __builtin_amdgcn_sinf(a1 * INV2PI);
        float cs1 = __builtin_amdgcn_cosf(a1 * INV2PI);

        const float DX[4] = {0.5f, -0.5f, -0.5f, 0.5f};
        const float DY[4] = {0.5f,  0.5f, -0.5f, -0.5f};
        float c1x[4], c1y[4], c2x[4], c2y[4];
        #pragma unroll
        for (int k = 0; k < 4; ++k) {
            float cx = DX[k] * w1, cy = DY[k] * h1;
            c1x[k] = cx * cs1 - cy * sn1 + x1c;
            c1y[k] = cx * sn1 + cy * cs1 + y1c;
            float gx = DX[k] * w2, gy = DY[k] * h2;
            c2x[k] = gx * cs2 - gy * sn2 + x2c;
            c2y[k] = gx * sn2 + gy * cs2 + y2c;
        }

        float vx[24], vy[24];
        unsigned vmask = 0;
        float sx = 0.f, sy = 0.f;

        // corner containment (reference-exact predicates), slots 0..7
        {
            float abx = c2x[1] - c2x[0], aby = c2y[1] - c2y[0];
            float adx = c2x[3] - c2x[0], ady = c2y[3] - c2y[0];
            float iab = frcp(abx * abx + aby * aby);
            float iad = frcp(adx * adx + ady * ady);
            #pragma unroll
            for (int k = 0; k < 4; ++k) {
                float amx = c1x[k] - c2x[0], amy = c1y[k] - c2y[0];
                float pab = (abx * amx + aby * amy) * iab;
                float pad = (adx * amx + ady * amy) * iad;
                bool ok = (pab > -1e-6f) && (pab < 1.f + 1e-6f) &&
                          (pad > -1e-6f) && (pad < 1.f + 1e-6f);
                vx[k] = c1x[k]; vy[k] = c1y[k];
                vmask |= ok ? (1u << k) : 0u;
                sx += ok ? c1x[k] : 0.f;
                sy += ok ? c1y[k] : 0.f;
            }
            abx = c1x[1] - c1x[0]; aby = c1y[1] - c1y[0];
            adx = c1x[3] - c1x[0]; ady = c1y[3] - c1y[0];
            iab = frcp(abx * abx + aby * aby);
            iad = frcp(adx * adx + ady * ady);
            #pragma unroll
            for (int k = 0; k < 4; ++k) {
                float amx = c2x[k] - c1x[0], amy = c2y[k] - c1y[0];
                float pab = (abx * amx + aby * amy) * iab;
                float pad = (adx * amx + ady * amy) * iad;
                bool ok = (pab > -1e-6f) && (pab < 1.f + 1e-6f) &&
                          (pad > -1e-6f) && (pad < 1.f + 1e-6f);
                vx[4 + k] = c2x[k]; vy[4 + k] = c2y[k];
                vmask |= ok ? (1u << (4 + k)) : 0u;
                sx += ok ? c2x[k] : 0.f;
                sy += ok ? c2y[k] : 0.f;
            }
        }

        // 16 edge-pair points, slots 8..23 — REFERENCE-EXACT formulas
        // (reference's t is the NEGATED standard parameter; replicate, not fix)
        #pragma unroll
        for (int ii = 0; ii < 4; ++ii) {
            float ex1 = c1x[ii],       ey1 = c1y[ii];
            float ex2 = c1x[(ii+1)&3], ey2 = c1y[(ii+1)&3];
            #pragma unroll
            for (int jj = 0; jj < 4; ++jj) {
                float ex3 = c2x[jj],       ey3 = c2y[jj];
                float ex4 = c2x[(jj+1)&3], ey4 = c2y[(jj+1)&3];
                float num  = (ex2-ex1)*(ey3-ey4) - (ey2-ey1)*(ex3-ex4);
                float dent = (ex1-ex3)*(ey3-ey4) - (ey1-ey3)*(ex3-ex4);
                float denu = (ex1-ex3)*(ey1-ey2) - (ey1-ey3)*(ex1-ex2);
                float rn = frcp(num + EPS_F);
                float t = dent * rn;
                float u = -denu * rn;
                bool ok = (t > 0.f) && (t < 1.f) && (u > 0.f) && (u < 1.f) && (num != 0.f);
                int idx = 8 + ii*4 + jj;
                float px_ = ex1 + t * (ex2 - ex1);
                float py_ = ey1 + t * (ey2 - ey1);
                vx[idx] = px_; vy[idx] = py_;
                vmask |= ok ? (1u << idx) : 0u;
                sx += ok ? px_ : 0.f;
                sy += ok ? py_ : 0.f;
            }
        }

        int nv = __popc(vmask);
        float rdn = frcp((float)(nv < 1 ? 1 : nv));
        float mx = sx * rdn, my = sy * rdn;

        // angle pass: centroid-relative coords + sortable u32 key
        // (pseudo-angle monotone in atan2; low 5 bits = index for stable ties)
        unsigned kk[24];
        #pragma unroll
        for (int k = 0; k < 24; ++k) {
            float dx = vx[k] - mx, dy = vy[k] - my;
            vx[k] = dx; vy[k] = dy;
            float ax = fabsf(dx), ay = fabsf(dy);
            float dd = ax + ay;
            float tt = (dd > 0.f) ? dy * frcp(dd) : 0.f;
            float p  = (dx >= 0.f) ? tt
                     : (__builtin_signbitf(dy) ? (-2.f - tt) : (2.f - tt));
            int sb = __float_as_int(p);
            unsigned u = (unsigned)sb ^ (unsigned)((sb >> 31) | 0x80000000);
            bool v = (vmask >> k) & 1u;
            kk[k] = v ? ((u & 0xFFFFFFE0u) | (unsigned)k)
                      : (0xFFFFFFE0u | (unsigned)k);   // +inf region
        }

        // Batcher odd-even mergesort (32-net pruned to slots <24; validated
        // rounds 3&4), key + (x,y) payload — everything stays in VGPRs
        #pragma unroll
        for (int pb = 1; pb < 32; pb <<= 1) {
          #pragma unroll
          for (int qb = pb; qb >= 1; qb >>= 1) {
            #pragma unroll
            for (int jb = qb % pb; jb + qb < 32; jb += 2 * qb) {
              #pragma unroll
              for (int ib = 0; ib < qb; ++ib) {
                int a = jb + ib, b = jb + ib + qb;
                if (b < 24 && (a / (2 * pb)) == (b / (2 * pb))) {
                    bool sw = kk[b] < kk[a];
                    unsigned tk = kk[a]; float tx = vx[a], ty = vy[a];
                    kk[a] = sw ? kk[b] : tk;  vx[a] = sw ? vx[b] : tx;  vy[a] = sw ? vy[b] : ty;
                    kk[b] = sw ? tk : kk[b];  vx[b] = sw ? tx : vx[b];  vy[b] = sw ? ty : vy[b];
                }
              }
            }
          }
        }

        // shoelace over sorted (centroid-relative) vertices; positions >= nv
        // padded with first sorted vertex; 23 open-chain cross terms (ref-exact)
        float fx = vx[0], fy = vy[0];
        float prx = fx, pry = fy;
        float area2 = 0.f;
        #pragma unroll
        for (int k = 1; k < 24; ++k) {
            bool use = (k < nv);
            float cx_ = use ? vx[k] : fx;
            float cy_ = use ? vy[k] : fy;
            area2 += prx * cy_ - pry * cx_;
            prx = cx_; pry = cy_;
        }
        float inter2d = fabsf(area2) * 0.5f;

        // 3D extension
        float z1 = b1[2], d1 = b1[5], z2 = b2[2], d2 = b2[5];
        float zmax = fminf(z1 + d1 * 0.5f, z2 + d2 * 0.5f);
        float zmin = fmaxf(z1 - d1 * 0.5f, z2 - d2 * 0.5f);
        float inter3d = inter2d * fmaxf(zmax - zmin, 0.f);
        float vol1 = w1 * h1 * d1;
        float vol2 = w2 * h2 * d2;
        float iou = inter3d / (vol1 + vol2 - inter3d);
        float target = iou * 2.f - 1.f;
        wabs = fabsf(pred_iou[i] - target) * m;
    }

    // block reduction: wave shfl-xor, then LDS across 4 waves, then atomic
    #pragma unroll
    for (int off = 32; off > 0; off >>= 1) {
        wabs += __shfl_xor(wabs, off);
        mval += __shfl_xor(mval, off);
    }
    __shared__ float sw_[4], sm_[4];
    int lane = threadIdx.x & 63;
    int wid  = threadIdx.x >> 6;
    if (lane == 0) { sw_[wid] = wabs; sm_[wid] = mval; }
    __syncthreads();
    if (threadIdx.x == 0) {
        float tw = sw_[0] + sw_[1] + sw_[2] + sw_[3];
        float tm = sm_[0] + sm_[1] + sm_[2] + sm_[3];
        atomicAdd(&acc[0], (double)tw);
        atomicAdd(&acc[1], (double)tm);
    }
}

__global__ void __launch_bounds__(64) iou3d_final(const double* __restrict__ acc,
                                                  float* __restrict__ out) {
    if (threadIdx.x == 0 && blockIdx.x == 0) {
        double s  = acc[0];
        double dm = acc[1];
        double denom = dm > 1e-4 ? dm : 1e-4;
        out[0] = (float)(s / denom);   // LOSS_WEIGHT = 1
    }
}

extern "C" void kernel_launch(void* const* d_in, const int* in_sizes, int n_in,
                              void* d_out, int out_size, void* d_ws, size_t ws_size,
                              hipStream_t stream) {
    const float* pred_iou   = (const float*)d_in[0];
    const float* pred_boxes = (const float*)d_in[1];
    const float* gt_boxes   = (const float*)d_in[2];
    const int*   mask       = (const int*)d_in[3];
    float* out = (float*)d_out;
    double* acc = (double*)d_ws;

    int N = in_sizes[0];
    int blocks = (N + 255) / 256;

    iou3d_init<<<1, 64, 0, stream>>>(acc);
    iou3d_main<<<blocks, 256, 0, stream>>>(pred_iou, pred_boxes, gt_boxes, mask, acc, N);
    iou3d_final<<<1, 64, 0, stream>>>(acc, out);
}

// Round 7
// 66.301 us; speedup vs baseline: 1.6340x; 1.6340x over previous
//
#include <hip/hip_runtime.h>
#include <math.h>

#define EPS_F 1e-8f

__device__ __forceinline__ float frcp(float x) { return __builtin_amdgcn_rcpf(x); }

typedef __fp16 h2f __attribute__((ext_vector_type(2)));

__device__ __forceinline__ unsigned packh2(float x, float y) {
    h2f h = __builtin_amdgcn_cvt_pkrtz(x, y);   // v_cvt_pkrtz_f16_f32
    return __builtin_bit_cast(unsigned, h);
}
__device__ __forceinline__ void unpackh2(unsigned u, float& x, float& y) {
    h2f h = __builtin_bit_cast(h2f, u);
    x = (float)h.x; y = (float)h.y;
}

__global__ void __launch_bounds__(64) iou3d_init(double* acc) {
    if (threadIdx.x == 0) { acc[0] = 0.0; acc[1] = 0.0; }
}

__global__ void __launch_bounds__(256) iou3d_main(
    const float* __restrict__ pred_iou,
    const float* __restrict__ pred_boxes,   // N x 7: x y z w l h yaw
    const float* __restrict__ gt_boxes,     // N x 8: x y z w l h sin cos
    const int*   __restrict__ mask,
    double* __restrict__ acc,
    int N)
{
    // per-thread vertex scratch: 24 x packed-f16 (x,y), stride 25 dwords.
    // odd stride -> gcd(25,32)=1 -> 2 lanes/bank across wave64 = conflict-free.
    // 256 threads * 100 B = 25.6 KB -> 6 blocks/CU -> 75% occupancy ceiling.
    __shared__ unsigned vbuf[256 * 25];
    const int dbase = threadIdx.x * 25;

    int i = blockIdx.x * blockDim.x + threadIdx.x;
    float wabs = 0.f, mval = 0.f;

    if (i < N) {
        const float* b1 = pred_boxes + (size_t)i * 7;
        const float* b2 = gt_boxes   + (size_t)i * 8;
        float m = (float)mask[i];
        mval = m;

        float x1c = b1[0], y1c = b1[1], w1 = b1[3], h1 = b1[4], a1 = b1[6];
        float w2 = b2[3], h2 = b2[4];
        float s2v = b2[6], c2v = b2[7];
        // work in frame relative to pred-box center (translation-invariant
        // formulas; keeps coords ~|6| so f16 storage has ~1e-3 rel precision)
        float tx2 = b2[0] - x1c, ty2 = b2[1] - y1c;

        // cos/sin of gt yaw without atan2: cos(atan2(s,c)) = c/sqrt(s^2+c^2)
        float invn = rsqrtf(s2v * s2v + c2v * c2v);
        float cs2 = c2v * invn, sn2 = s2v * invn;
        // pred yaw in [-pi,pi]: raw v_sin/v_cos (input in revolutions)
        const float INV2PI = 0.15915494309189535f;
        float sn1 = __builtin_amdgcn_sinf(a1 * INV2PI);
        float cs1 = __builtin_amdgcn_cosf(a1 * INV2PI);

        const float DX[4] = {0.5f, -0.5f, -0.5f, 0.5f};
        const float DY[4] = {0.5f,  0.5f, -0.5f, -0.5f};
        float c1x[4], c1y[4], c2x[4], c2y[4];
        #pragma unroll
        for (int k = 0; k < 4; ++k) {
            float cx = DX[k] * w1, cy = DY[k] * h1;
            c1x[k] = cx * cs1 - cy * sn1;
            c1y[k] = cx * sn1 + cy * cs1;
            float gx = DX[k] * w2, gy = DY[k] * h2;
            c2x[k] = gx * cs2 - gy * sn2 + tx2;
            c2y[k] = gx * sn2 + gy * cs2 + ty2;
        }

        unsigned vmask = 0;
        float sx = 0.f, sy = 0.f;   // f32 sums of valid vertices (rel frame)

        // corner containment (reference-exact predicates), slots 0..7
        {
            float abx = c2x[1] - c2x[0], aby = c2y[1] - c2y[0];
            float adx = c2x[3] - c2x[0], ady = c2y[3] - c2y[0];
            float iab = frcp(abx * abx + aby * aby);
            float iad = frcp(adx * adx + ady * ady);
            #pragma unroll
            for (int k = 0; k < 4; ++k) {
                float amx = c1x[k] - c2x[0], amy = c1y[k] - c2y[0];
                float pab = (abx * amx + aby * amy) * iab;
                float pad = (adx * amx + ady * amy) * iad;
                bool ok = (pab > -1e-6f) && (pab < 1.f + 1e-6f) &&
                          (pad > -1e-6f) && (pad < 1.f + 1e-6f);
                vbuf[dbase + k] = packh2(c1x[k], c1y[k]);
                vmask |= ok ? (1u << k) : 0u;
                sx += ok ? c1x[k] : 0.f;
                sy += ok ? c1y[k] : 0.f;
            }
            abx = c1x[1] - c1x[0]; aby = c1y[1] - c1y[0];
            adx = c1x[3] - c1x[0]; ady = c1y[3] - c1y[0];
            iab = frcp(abx * abx + aby * aby);
            iad = frcp(adx * adx + ady * ady);
            #pragma unroll
            for (int k = 0; k < 4; ++k) {
                float amx = c2x[k] - c1x[0], amy = c2y[k] - c1y[0];
                float pab = (abx * amx + aby * amy) * iab;
                float pad = (adx * amx + ady * amy) * iad;
                bool ok = (pab > -1e-6f) && (pab < 1.f + 1e-6f) &&
                          (pad > -1e-6f) && (pad < 1.f + 1e-6f);
                vbuf[dbase + 4 + k] = packh2(c2x[k], c2y[k]);
                vmask |= ok ? (1u << (4 + k)) : 0u;
                sx += ok ? c2x[k] : 0.f;
                sy += ok ? c2y[k] : 0.f;
            }
        }

        // 16 edge-pair points, slots 8..23 — REFERENCE-EXACT formulas
        // (reference's t is the NEGATED standard parameter; replicate, not fix)
        #pragma unroll
        for (int ii = 0; ii < 4; ++ii) {
            float ex1 = c1x[ii],       ey1 = c1y[ii];
            float ex2 = c1x[(ii+1)&3], ey2 = c1y[(ii+1)&3];
            #pragma unroll
            for (int jj = 0; jj < 4; ++jj) {
                float ex3 = c2x[jj],       ey3 = c2y[jj];
                float ex4 = c2x[(jj+1)&3], ey4 = c2y[(jj+1)&3];
                float num  = (ex2-ex1)*(ey3-ey4) - (ey2-ey1)*(ex3-ex4);
                float dent = (ex1-ex3)*(ey3-ey4) - (ey1-ey3)*(ex3-ex4);
                float denu = (ex1-ex3)*(ey1-ey2) - (ey1-ey3)*(ex1-ex2);
                float rn = frcp(num + EPS_F);
                float t = dent * rn;
                float u = -denu * rn;
                bool ok = (t > 0.f) && (t < 1.f) && (u > 0.f) && (u < 1.f) && (num != 0.f);
                int idx = 8 + ii*4 + jj;
                float px_ = ex1 + t * (ex2 - ex1);
                float py_ = ey1 + t * (ey2 - ey1);
                vbuf[dbase + idx] = packh2(px_, py_);
                vmask |= ok ? (1u << idx) : 0u;
                sx += ok ? px_ : 0.f;
                sy += ok ? py_ : 0.f;
            }
        }

        int nv = __popc(vmask);
        float rdn = frcp((float)(nv < 1 ? 1 : nv));
        float mx = sx * rdn, my = sy * rdn;

        // angle pass: pseudo-angle (monotone in atan2) -> sortable u32,
        // low 5 bits = index (stable tiebreak, matches stable argsort)
        unsigned kk[24];
        #pragma unroll
        for (int k = 0; k < 24; ++k) {
            float x_, y_;
            unpackh2(vbuf[dbase + k], x_, y_);
            float dx = x_ - mx, dy = y_ - my;
            float ax = fabsf(dx), ay = fabsf(dy);
            float dd = ax + ay;
            float tt = (dd > 0.f) ? dy * frcp(dd) : 0.f;
            float p  = (dx >= 0.f) ? tt
                     : (__builtin_signbitf(dy) ? (-2.f - tt) : (2.f - tt));
            int sb = __float_as_int(p);
            unsigned u = (unsigned)sb ^ (unsigned)((sb >> 31) | 0x80000000);
            bool v = (vmask >> k) & 1u;
            kk[k] = v ? ((u & 0xFFFFFFE0u) | (unsigned)k)
                      : (0xFFFFFFE0u | (unsigned)k);   // +inf region
        }

        // Batcher odd-even mergesort (32-net pruned to slots <24; validated
        // rounds 3-5), 1-wide u32 payload: CE = v_min_u32 + v_max_u32
        #pragma unroll
        for (int pb = 1; pb < 32; pb <<= 1) {
          #pragma unroll
          for (int qb = pb; qb >= 1; qb >>= 1) {
            #pragma unroll
            for (int jb = qb % pb; jb + qb < 32; jb += 2 * qb) {
              #pragma unroll
              for (int ib = 0; ib < qb; ++ib) {
                int a = jb + ib, b = jb + ib + qb;
                if (b < 24 && (a / (2 * pb)) == (b / (2 * pb))) {
                    unsigned ka = kk[a], kb2 = kk[b];
                    kk[a] = ka < kb2 ? ka : kb2;
                    kk[b] = ka < kb2 ? kb2 : ka;
                }
              }
            }
          }
        }

        // shoelace in centroid-relative coords, gather by sorted index;
        // positions >= nv padded with first sorted vertex (reference-exact)
        float area2 = 0.f, fx = 0.f, fy = 0.f, px = 0.f, py = 0.f;
        #pragma unroll
        for (int k = 0; k < 24; ++k) {
            float x_, y_;
            unpackh2(vbuf[dbase + (kk[k] & 31u)], x_, y_);
            float x = x_ - mx, y = y_ - my;
            if (k == 0) { fx = x; fy = y; px = x; py = y; }
            else {
                bool use = (k < nv);
                float cx_ = use ? x : fx;
                float cy_ = use ? y : fy;
                area2 += px * cy_ - py * cx_;
                px = cx_; py = cy_;
            }
        }
        float inter2d = fabsf(area2) * 0.5f;

        // 3D extension
        float z1 = b1[2], d1 = b1[5], z2 = b2[2], d2 = b2[5];
        float zmax = fminf(z1 + d1 * 0.5f, z2 + d2 * 0.5f);
        float zmin = fmaxf(z1 - d1 * 0.5f, z2 - d2 * 0.5f);
        float inter3d = inter2d * fmaxf(zmax - zmin, 0.f);
        float vol1 = w1 * h1 * d1;
        float vol2 = b2[3] * b2[4] * d2;
        float iou = inter3d / (vol1 + vol2 - inter3d);
        float target = iou * 2.f - 1.f;
        wabs = fabsf(pred_iou[i] - target) * m;
    }

    // block reduction: wave shfl-xor, then LDS across 4 waves, then atomic
    #pragma unroll
    for (int off = 32; off > 0; off >>= 1) {
        wabs += __shfl_xor(wabs, off);
        mval += __shfl_xor(mval, off);
    }
    __shared__ float sw_[4], sm_[4];
    int lane = threadIdx.x & 63;
    int wid  = threadIdx.x >> 6;
    if (lane == 0) { sw_[wid] = wabs; sm_[wid] = mval; }
    __syncthreads();
    if (threadIdx.x == 0) {
        float tw = sw_[0] + sw_[1] + sw_[2] + sw_[3];
        float tm = sm_[0] + sm_[1] + sm_[2] + sm_[3];
        atomicAdd(&acc[0], (double)tw);
        atomicAdd(&acc[1], (double)tm);
    }
}

__global__ void __launch_bounds__(64) iou3d_final(const double* __restrict__ acc,
                                                  float* __restrict__ out) {
    if (threadIdx.x == 0 && blockIdx.x == 0) {
        double s  = acc[0];
        double dm = acc[1];
        double denom = dm > 1e-4 ? dm : 1e-4;
        out[0] = (float)(s / denom);   // LOSS_WEIGHT = 1
    }
}

extern "C" void kernel_launch(void* const* d_in, const int* in_sizes, int n_in,
                              void* d_out, int out_size, void* d_ws, size_t ws_size,
                              hipStream_t stream) {
    const float* pred_iou   = (const float*)d_in[0];
    const float* pred_boxes = (const float*)d_in[1];
    const float* gt_boxes   = (const float*)d_in[2];
    const int*   mask       = (const int*)d_in[3];
    float* out = (float*)d_out;
    double* acc = (double*)d_ws;

    int N = in_sizes[0];
    int blocks = (N + 255) / 256;

    iou3d_init<<<1, 64, 0, stream>>>(acc);
    iou3d_main<<<blocks, 256, 0, stream>>>(pred_iou, pred_boxes, gt_boxes, mask, acc, N);
    iou3d_final<<<1, 64, 0, stream>>>(acc, out);
}

// Round 8
// 64.708 us; speedup vs baseline: 1.6742x; 1.0246x over previous
//
#include <hip/hip_runtime.h>
#include <math.h>

#define EPS_F 1e-8f

__device__ __forceinline__ float frcp(float x) { return __builtin_amdgcn_rcpf(x); }

typedef __fp16 h2f __attribute__((ext_vector_type(2)));

__device__ __forceinline__ unsigned packh2(float x, float y) {
    h2f h = __builtin_amdgcn_cvt_pkrtz(x, y);   // v_cvt_pkrtz_f16_f32
    return __builtin_bit_cast(unsigned, h);
}
__device__ __forceinline__ void unpackh2(unsigned u, float& x, float& y) {
    h2f h = __builtin_bit_cast(h2f, u);
    x = (float)h.x; y = (float)h.y;
}

__global__ void __launch_bounds__(64) iou3d_init(double* acc) {
    if (threadIdx.x == 0) { acc[0] = 0.0; acc[1] = 0.0; }
}

__global__ void __launch_bounds__(256, 2) iou3d_main(
    const float* __restrict__ pred_iou,
    const float* __restrict__ pred_boxes,   // N x 7: x y z w l h yaw
    const float* __restrict__ gt_boxes,     // N x 8: x y z w l h sin cos
    const int*   __restrict__ mask,
    double* __restrict__ acc,
    int N)
{
    int i = blockIdx.x * blockDim.x + threadIdx.x;
    float wabs = 0.f, mval = 0.f;

    if (i < N) {
        const float* b1 = pred_boxes + (size_t)i * 7;
        const float* b2 = gt_boxes   + (size_t)i * 8;
        float m = (float)mask[i];
        mval = m;

        float x1c = b1[0], y1c = b1[1], w1 = b1[3], h1 = b1[4], a1 = b1[6];
        float w2 = b2[3], h2 = b2[4];
        float s2v = b2[6], c2v = b2[7];
        // frame relative to pred-box center (translation-invariant formulas;
        // coords ~|6| so f16 payload has ~1e-3 abs precision — validated
        // round 7: absmax 0.0)
        float tx2 = b2[0] - x1c, ty2 = b2[1] - y1c;

        // cos/sin of gt yaw without atan2: cos(atan2(s,c)) = c/sqrt(s^2+c^2)
        float invn = rsqrtf(s2v * s2v + c2v * c2v);
        float cs2 = c2v * invn, sn2 = s2v * invn;
        // pred yaw in [-pi,pi]: raw v_sin/v_cos (input in revolutions)
        const float INV2PI = 0.15915494309189535f;
        float sn1 = __builtin_amdgcn_sinf(a1 * INV2PI);
        float cs1 = __builtin_amdgcn_cosf(a1 * INV2PI);

        const float DX[4] = {0.5f, -0.5f, -0.5f, 0.5f};
        const float DY[4] = {0.5f,  0.5f, -0.5f, -0.5f};
        float c1x[4], c1y[4], c2x[4], c2y[4];
        #pragma unroll
        for (int k = 0; k < 4; ++k) {
            float cx = DX[k] * w1, cy = DY[k] * h1;
            c1x[k] = cx * cs1 - cy * sn1;
            c1y[k] = cx * sn1 + cy * cs1;
            float gx = DX[k] * w2, gy = DY[k] * h2;
            c2x[k] = gx * cs2 - gy * sn2 + tx2;
            c2y[k] = gx * sn2 + gy * cs2 + ty2;
        }

        unsigned pl[24];            // packed f16 (x,y) payload — registers only
        unsigned vmask = 0;
        float sx = 0.f, sy = 0.f;   // f32 sums of valid vertices

        // corner containment (reference-exact predicates), slots 0..7
        {
            float abx = c2x[1] - c2x[0], aby = c2y[1] - c2y[0];
            float adx = c2x[3] - c2x[0], ady = c2y[3] - c2y[0];
            float iab = frcp(abx * abx + aby * aby);
            float iad = frcp(adx * adx + ady * ady);
            #pragma unroll
            for (int k = 0; k < 4; ++k) {
                float amx = c1x[k] - c2x[0], amy = c1y[k] - c2y[0];
                float pab = (abx * amx + aby * amy) * iab;
                float pad = (adx * amx + ady * amy) * iad;
                bool ok = (pab > -1e-6f) && (pab < 1.f + 1e-6f) &&
                          (pad > -1e-6f) && (pad < 1.f + 1e-6f);
                pl[k] = packh2(c1x[k], c1y[k]);
                vmask |= ok ? (1u << k) : 0u;
                sx += ok ? c1x[k] : 0.f;
                sy += ok ? c1y[k] : 0.f;
            }
            abx = c1x[1] - c1x[0]; aby = c1y[1] - c1y[0];
            adx = c1x[3] - c1x[0]; ady = c1y[3] - c1y[0];
            iab = frcp(abx * abx + aby * aby);
            iad = frcp(adx * adx + ady * ady);
            #pragma unroll
            for (int k = 0; k < 4; ++k) {
                float amx = c2x[k] - c1x[0], amy = c2y[k] - c1y[0];
                float pab = (abx * amx + aby * amy) * iab;
                float pad = (adx * amx + ady * amy) * iad;
                bool ok = (pab > -1e-6f) && (pab < 1.f + 1e-6f) &&
                          (pad > -1e-6f) && (pad < 1.f + 1e-6f);
                pl[4 + k] = packh2(c2x[k], c2y[k]);
                vmask |= ok ? (1u << (4 + k)) : 0u;
                sx += ok ? c2x[k] : 0.f;
                sy += ok ? c2y[k] : 0.f;
            }
        }

        // 16 edge-pair points, slots 8..23 — REFERENCE-EXACT formulas
        // (reference's t is the NEGATED standard parameter; replicate, not fix)
        #pragma unroll
        for (int ii = 0; ii < 4; ++ii) {
            float ex1 = c1x[ii],       ey1 = c1y[ii];
            float ex2 = c1x[(ii+1)&3], ey2 = c1y[(ii+1)&3];
            #pragma unroll
            for (int jj = 0; jj < 4; ++jj) {
                float ex3 = c2x[jj],       ey3 = c2y[jj];
                float ex4 = c2x[(jj+1)&3], ey4 = c2y[(jj+1)&3];
                float num  = (ex2-ex1)*(ey3-ey4) - (ey2-ey1)*(ex3-ex4);
                float dent = (ex1-ex3)*(ey3-ey4) - (ey1-ey3)*(ex3-ex4);
                float denu = (ex1-ex3)*(ey1-ey2) - (ey1-ey3)*(ex1-ex2);
                float rn = frcp(num + EPS_F);
                float t = dent * rn;
                float u = -denu * rn;
                bool ok = (t > 0.f) && (t < 1.f) && (u > 0.f) && (u < 1.f) && (num != 0.f);
                int idx = 8 + ii*4 + jj;
                float px_ = ex1 + t * (ex2 - ex1);
                float py_ = ey1 + t * (ey2 - ey1);
                pl[idx] = packh2(px_, py_);
                vmask |= ok ? (1u << idx) : 0u;
                sx += ok ? px_ : 0.f;
                sy += ok ? py_ : 0.f;
            }
        }

        int nv = __popc(vmask);
        float rdn = frcp((float)(nv < 1 ? 1 : nv));
        float mx = sx * rdn, my = sy * rdn;

        // angle pass: unpack payload (f16 round-trip, same numerics as round 7),
        // pseudo-angle (monotone in atan2) -> sortable u32, low 5 bits = index
        unsigned kk[24];
        #pragma unroll
        for (int k = 0; k < 24; ++k) {
            float x_, y_;
            unpackh2(pl[k], x_, y_);
            float dx = x_ - mx, dy = y_ - my;
            float ax = fabsf(dx), ay = fabsf(dy);
            float dd = ax + ay;
            float tt = (dd > 0.f) ? dy * frcp(dd) : 0.f;
            float p  = (dx >= 0.f) ? tt
                     : (__builtin_signbitf(dy) ? (-2.f - tt) : (2.f - tt));
            int sb = __float_as_int(p);
            unsigned u = (unsigned)sb ^ (unsigned)((sb >> 31) | 0x80000000);
            bool v = (vmask >> k) & 1u;
            kk[k] = v ? ((u & 0xFFFFFFE0u) | (unsigned)k)
                      : (0xFFFFFFE0u | (unsigned)k);   // +inf region
        }

        // Batcher odd-even mergesort (32-net pruned to slots <24; validated
        // rounds 3-7), key + ONE packed payload reg:
        // CE = v_cmp + v_min_u32/v_max_u32 + 2 cndmask = 5 inst
        #pragma unroll
        for (int pb = 1; pb < 32; pb <<= 1) {
          #pragma unroll
          for (int qb = pb; qb >= 1; qb >>= 1) {
            #pragma unroll
            for (int jb = qb % pb; jb + qb < 32; jb += 2 * qb) {
              #pragma unroll
              for (int ib = 0; ib < qb; ++ib) {
                int a = jb + ib, b = jb + ib + qb;
                if (b < 24 && (a / (2 * pb)) == (b / (2 * pb))) {
                    bool sw = kk[b] < kk[a];
                    unsigned ka = kk[a], pa = pl[a];
                    kk[a] = sw ? kk[b] : ka;  pl[a] = sw ? pl[b] : pa;
                    kk[b] = sw ? ka : kk[b];  pl[b] = sw ? pa : pl[b];
                }
              }
            }
          }
        }

        // shoelace in centroid-relative coords over sorted payload (all static
        // indices); positions >= nv padded with first sorted vertex (ref-exact)
        float fx, fy;
        unpackh2(pl[0], fx, fy);
        fx -= mx; fy -= my;
        float prx = fx, pry = fy;
        float area2 = 0.f;
        #pragma unroll
        for (int k = 1; k < 24; ++k) {
            float x_, y_;
            unpackh2(pl[k], x_, y_);
            bool use = (k < nv);
            float cx_ = use ? (x_ - mx) : fx;
            float cy_ = use ? (y_ - my) : fy;
            area2 += prx * cy_ - pry * cx_;
            prx = cx_; pry = cy_;
        }
        float inter2d = fabsf(area2) * 0.5f;

        // 3D extension
        float z1 = b1[2], d1 = b1[5], z2 = b2[2], d2 = b2[5];
        float zmax = fminf(z1 + d1 * 0.5f, z2 + d2 * 0.5f);
        float zmin = fmaxf(z1 - d1 * 0.5f, z2 - d2 * 0.5f);
        float inter3d = inter2d * fmaxf(zmax - zmin, 0.f);
        float vol1 = w1 * h1 * d1;
        float vol2 = b2[3] * b2[4] * d2;
        float iou = inter3d / (vol1 + vol2 - inter3d);
        float target = iou * 2.f - 1.f;
        wabs = fabsf(pred_iou[i] - target) * m;
    }

    // block reduction: wave shfl-xor, then LDS across 4 waves, then atomic
    #pragma unroll
    for (int off = 32; off > 0; off >>= 1) {
        wabs += __shfl_xor(wabs, off);
        mval += __shfl_xor(mval, off);
    }
    __shared__ float sw_[4], sm_[4];
    int lane = threadIdx.x & 63;
    int wid  = threadIdx.x >> 6;
    if (lane == 0) { sw_[wid] = wabs; sm_[wid] = mval; }
    __syncthreads();
    if (threadIdx.x == 0) {
        float tw = sw_[0] + sw_[1] + sw_[2] + sw_[3];
        float tm = sm_[0] + sm_[1] + sm_[2] + sm_[3];
        atomicAdd(&acc[0], (double)tw);
        atomicAdd(&acc[1], (double)tm);
    }
}

__global__ void __launch_bounds__(64) iou3d_final(const double* __restrict__ acc,
                                                  float* __restrict__ out) {
    if (threadIdx.x == 0 && blockIdx.x == 0) {
        double s  = acc[0];
        double dm = acc[1];
        double denom = dm > 1e-4 ? dm : 1e-4;
        out[0] = (float)(s / denom);   // LOSS_WEIGHT = 1
    }
}

extern "C" void kernel_launch(void* const* d_in, const int* in_sizes, int n_in,
                              void* d_out, int out_size, void* d_ws, size_t ws_size,
                              hipStream_t stream) {
    const float* pred_iou   = (const float*)d_in[0];
    const float* pred_boxes = (const float*)d_in[1];
    const float* gt_boxes   = (const float*)d_in[2];
    const int*   mask       = (const int*)d_in[3];
    float* out = (float*)d_out;
    double* acc = (double*)d_ws;

    int N = in_sizes[0];
    int blocks = (N + 255) / 256;

    iou3d_init<<<1, 64, 0, stream>>>(acc);
    iou3d_main<<<blocks, 256, 0, stream>>>(pred_iou, pred_boxes, gt_boxes, mask, acc, N);
    iou3d_final<<<1, 64, 0, stream>>>(acc, out);
}

// Round 9
// 48.975 us; speedup vs baseline: 2.2120x; 1.3212x over previous
//
#include <hip/hip_runtime.h>
#include <math.h>

#define EPS_F 1e-8f

__device__ __forceinline__ float frcp(float x) { return __builtin_amdgcn_rcpf(x); }

typedef __fp16 h2f __attribute__((ext_vector_type(2)));

__device__ __forceinline__ unsigned packh2(float x, float y) {
    h2f h = __builtin_amdgcn_cvt_pkrtz(x, y);   // v_cvt_pkrtz_f16_f32
    return __builtin_bit_cast(unsigned, h);
}
__device__ __forceinline__ void unpackh2(unsigned u, float& x, float& y) {
    h2f h = __builtin_bit_cast(h2f, u);
    x = (float)h.x; y = (float)h.y;
}

__global__ void __launch_bounds__(64) iou3d_init(double* acc) {
    if (threadIdx.x == 0) { acc[0] = 0.0; acc[1] = 0.0; }
}

struct Tail {
    float mx, my, zov, vsum, pi, mm;
    int nv;
};

// Build candidate vertices + sort keys for one element. Reference-exact
// semantics (validated rounds 3-8: absmax 0.0). Inactive lanes (i>=N) are
// clamped to a real element and masked out via mm=0 (keeps math NaN-free).
__device__ __forceinline__ void build(
    int i, const float* __restrict__ pred_iou,
    const float* __restrict__ pred_boxes, const float* __restrict__ gt_boxes,
    const int* __restrict__ mask, int N,
    unsigned kk[24], unsigned pl[24], Tail& o)
{
    int ic = i < N ? i : (N - 1);
    o.mm = (i < N) ? (float)mask[ic] : 0.f;
    const float* b1 = pred_boxes + (size_t)ic * 7;
    const float* b2 = gt_boxes   + (size_t)ic * 8;

    float x1c = b1[0], y1c = b1[1], w1 = b1[3], h1 = b1[4], a1 = b1[6];
    float w2 = b2[3], h2 = b2[4];
    float s2v = b2[6], c2v = b2[7];
    // frame relative to pred-box center (translation-invariant; coords ~|6|
    // so f16 payload is exact enough — round 7/8: absmax 0.0)
    float tx2 = b2[0] - x1c, ty2 = b2[1] - y1c;

    // cos/sin of gt yaw without atan2
    float invn = rsqrtf(s2v * s2v + c2v * c2v);
    float cs2 = c2v * invn, sn2 = s2v * invn;
    const float INV2PI = 0.15915494309189535f;
    float sn1 = __builtin_amdgcn_sinf(a1 * INV2PI);
    float cs1 = __builtin_amdgcn_cosf(a1 * INV2PI);

    const float DX[4] = {0.5f, -0.5f, -0.5f, 0.5f};
    const float DY[4] = {0.5f,  0.5f, -0.5f, -0.5f};
    float c1x[4], c1y[4], c2x[4], c2y[4];
    #pragma unroll
    for (int k = 0; k < 4; ++k) {
        float cx = DX[k] * w1, cy = DY[k] * h1;
        c1x[k] = cx * cs1 - cy * sn1;
        c1y[k] = cx * sn1 + cy * cs1;
        float gx = DX[k] * w2, gy = DY[k] * h2;
        c2x[k] = gx * cs2 - gy * sn2 + tx2;
        c2y[k] = gx * sn2 + gy * cs2 + ty2;
    }

    unsigned vmask = 0;
    float sx = 0.f, sy = 0.f;

    // corner containment (reference-exact predicates), slots 0..7
    {
        float abx = c2x[1] - c2x[0], aby = c2y[1] - c2y[0];
        float adx = c2x[3] - c2x[0], ady = c2y[3] - c2y[0];
        float iab = frcp(abx * abx + aby * aby);
        float iad = frcp(adx * adx + ady * ady);
        #pragma unroll
        for (int k = 0; k < 4; ++k) {
            float amx = c1x[k] - c2x[0], amy = c1y[k] - c2y[0];
            float pab = (abx * amx + aby * amy) * iab;
            float pad = (adx * amx + ady * amy) * iad;
            bool ok = (pab > -1e-6f) && (pab < 1.f + 1e-6f) &&
                      (pad > -1e-6f) && (pad < 1.f + 1e-6f);
            pl[k] = packh2(c1x[k], c1y[k]);
            vmask |= ok ? (1u << k) : 0u;
            sx += ok ? c1x[k] : 0.f;
            sy += ok ? c1y[k] : 0.f;
        }
        abx = c1x[1] - c1x[0]; aby = c1y[1] - c1y[0];
        adx = c1x[3] - c1x[0]; ady = c1y[3] - c1y[0];
        iab = frcp(abx * abx + aby * aby);
        iad = frcp(adx * adx + ady * ady);
        #pragma unroll
        for (int k = 0; k < 4; ++k) {
            float amx = c2x[k] - c1x[0], amy = c2y[k] - c1y[0];
            float pab = (abx * amx + aby * amy) * iab;
            float pad = (adx * amx + ady * amy) * iad;
            bool ok = (pab > -1e-6f) && (pab < 1.f + 1e-6f) &&
                      (pad > -1e-6f) && (pad < 1.f + 1e-6f);
            pl[4 + k] = packh2(c2x[k], c2y[k]);
            vmask |= ok ? (1u << (4 + k)) : 0u;
            sx += ok ? c2x[k] : 0.f;
            sy += ok ? c2y[k] : 0.f;
        }
    }

    // 16 edge-pair points, slots 8..23 — REFERENCE-EXACT formulas
    // (reference's t is the NEGATED standard parameter; replicate, not fix)
    #pragma unroll
    for (int ii = 0; ii < 4; ++ii) {
        float ex1 = c1x[ii],       ey1 = c1y[ii];
        float ex2 = c1x[(ii+1)&3], ey2 = c1y[(ii+1)&3];
        #pragma unroll
        for (int jj = 0; jj < 4; ++jj) {
            float ex3 = c2x[jj],       ey3 = c2y[jj];
            float ex4 = c2x[(jj+1)&3], ey4 = c2y[(jj+1)&3];
            float num  = (ex2-ex1)*(ey3-ey4) - (ey2-ey1)*(ex3-ex4);
            float dent = (ex1-ex3)*(ey3-ey4) - (ey1-ey3)*(ex3-ex4);
            float denu = (ex1-ex3)*(ey1-ey2) - (ey1-ey3)*(ex1-ex2);
            float rn = frcp(num + EPS_F);
            float t = dent * rn;
            float u = -denu * rn;
            bool ok = (t > 0.f) && (t < 1.f) && (u > 0.f) && (u < 1.f) && (num != 0.f);
            int idx = 8 + ii*4 + jj;
            float px_ = ex1 + t * (ex2 - ex1);
            float py_ = ey1 + t * (ey2 - ey1);
            pl[idx] = packh2(px_, py_);
            vmask |= ok ? (1u << idx) : 0u;
            sx += ok ? px_ : 0.f;
            sy += ok ? py_ : 0.f;
        }
    }

    int nv = __popc(vmask);
    float rdn = frcp((float)(nv < 1 ? 1 : nv));
    float mx = sx * rdn, my = sy * rdn;

    // pseudo-angle (monotone in atan2) -> sortable u32, low 5 bits = index
    #pragma unroll
    for (int k = 0; k < 24; ++k) {
        float x_, y_;
        unpackh2(pl[k], x_, y_);
        float dx = x_ - mx, dy = y_ - my;
        float ax = fabsf(dx), ay = fabsf(dy);
        float dd = ax + ay;
        float tt = (dd > 0.f) ? dy * frcp(dd) : 0.f;
        float p  = (dx >= 0.f) ? tt
                 : (__builtin_signbitf(dy) ? (-2.f - tt) : (2.f - tt));
        int sb = __float_as_int(p);
        unsigned u = (unsigned)sb ^ (unsigned)((sb >> 31) | 0x80000000);
        bool v = (vmask >> k) & 1u;
        kk[k] = v ? ((u & 0xFFFFFFE0u) | (unsigned)k)
                  : (0xFFFFFFE0u | (unsigned)k);   // +inf region
    }

    o.mx = mx; o.my = my; o.nv = nv;
    float z1 = b1[2], d1 = b1[5], z2 = b2[2], d2 = b2[5];
    float zmax = fminf(z1 + d1 * 0.5f, z2 + d2 * 0.5f);
    float zmin = fmaxf(z1 - d1 * 0.5f, z2 - d2 * 0.5f);
    o.zov  = fmaxf(zmax - zmin, 0.f);
    o.vsum = w1 * h1 * d1 + w2 * h2 * d2;
    o.pi   = pred_iou[ic];
}

// compare-exchange: keys via umin/umax (short chain feeding next stage),
// payload cndmask hangs off-path
__device__ __forceinline__ void ce(unsigned& ka, unsigned& kb,
                                   unsigned& pa, unsigned& pb) {
    bool sw = kb < ka;
    unsigned mn = ka < kb ? ka : kb;   // v_min_u32
    unsigned mx = ka < kb ? kb : ka;   // v_max_u32
    unsigned qa = sw ? pb : pa;
    unsigned qb = sw ? pa : pb;
    ka = mn; kb = mx; pa = qa; pb = qb;
}

__global__ void __launch_bounds__(256, 2) iou3d_main(
    const float* __restrict__ pred_iou,
    const float* __restrict__ pred_boxes,
    const float* __restrict__ gt_boxes,
    const int*   __restrict__ mask,
    double* __restrict__ acc,
    int N)
{
    int tid = blockIdx.x * blockDim.x + threadIdx.x;
    int iA = tid * 2, iB = tid * 2 + 1;

    unsigned kkA[24], plA[24], kkB[24], plB[24];
    Tail tA, tB;
    build(iA, pred_iou, pred_boxes, gt_boxes, mask, N, kkA, plA, tA);
    build(iB, pred_iou, pred_boxes, gt_boxes, mask, N, kkB, plB, tB);

    // Batcher odd-even mergesort (32-net pruned to slots <24; validated
    // rounds 3-8), two independent networks interleaved CE-by-CE for ILP
    #pragma unroll
    for (int pb = 1; pb < 32; pb <<= 1) {
      #pragma unroll
      for (int qb = pb; qb >= 1; qb >>= 1) {
        #pragma unroll
        for (int jb = qb % pb; jb + qb < 32; jb += 2 * qb) {
          #pragma unroll
          for (int ib = 0; ib < qb; ++ib) {
            int a = jb + ib, b = jb + ib + qb;
            if (b < 24 && (a / (2 * pb)) == (b / (2 * pb))) {
                ce(kkA[a], kkA[b], plA[a], plA[b]);
                ce(kkB[a], kkB[b], plB[a], plB[b]);
            }
          }
        }
      }
    }

    // shoelace over sorted centroid-relative vertices, A/B interleaved;
    // positions >= nv padded with first sorted vertex (reference-exact)
    float fxA, fyA, fxB, fyB;
    unpackh2(plA[0], fxA, fyA); fxA -= tA.mx; fyA -= tA.my;
    unpackh2(plB[0], fxB, fyB); fxB -= tB.mx; fyB -= tB.my;
    float prxA = fxA, pryA = fyA, areaA = 0.f;
    float prxB = fxB, pryB = fyB, areaB = 0.f;
    #pragma unroll
    for (int k = 1; k < 24; ++k) {
        float xA, yA, xB, yB;
        unpackh2(plA[k], xA, yA);
        unpackh2(plB[k], xB, yB);
        bool useA = (k < tA.nv), useB = (k < tB.nv);
        float cxA = useA ? (xA - tA.mx) : fxA;
        float cyA = useA ? (yA - tA.my) : fyA;
        float cxB = useB ? (xB - tB.mx) : fxB;
        float cyB = useB ? (yB - tB.my) : fyB;
        areaA += prxA * cyA - pryA * cxA;
        areaB += prxB * cyB - pryB * cxB;
        prxA = cxA; pryA = cyA;
        prxB = cxB; pryB = cyB;
    }

    float i2A = fabsf(areaA) * 0.5f;
    float i2B = fabsf(areaB) * 0.5f;
    float i3A = i2A * tA.zov;
    float i3B = i2B * tB.zov;
    float iouA = i3A / (tA.vsum - i3A);
    float iouB = i3B / (tB.vsum - i3B);
    float wabs = fabsf(tA.pi - (iouA * 2.f - 1.f)) * tA.mm
               + fabsf(tB.pi - (iouB * 2.f - 1.f)) * tB.mm;
    float mval = tA.mm + tB.mm;

    // block reduction: wave shfl-xor, then LDS across 4 waves, then atomic
    #pragma unroll
    for (int off = 32; off > 0; off >>= 1) {
        wabs += __shfl_xor(wabs, off);
        mval += __shfl_xor(mval, off);
    }
    __shared__ float sw_[4], sm_[4];
    int lane = threadIdx.x & 63;
    int wid  = threadIdx.x >> 6;
    if (lane == 0) { sw_[wid] = wabs; sm_[wid] = mval; }
    __syncthreads();
    if (threadIdx.x == 0) {
        float tw = sw_[0] + sw_[1] + sw_[2] + sw_[3];
        float tm = sm_[0] + sm_[1] + sm_[2] + sm_[3];
        atomicAdd(&acc[0], (double)tw);
        atomicAdd(&acc[1], (double)tm);
    }
}

__global__ void __launch_bounds__(64) iou3d_final(const double* __restrict__ acc,
                                                  float* __restrict__ out) {
    if (threadIdx.x == 0 && blockIdx.x == 0) {
        double s  = acc[0];
        double dm = acc[1];
        double denom = dm > 1e-4 ? dm : 1e-4;
        out[0] = (float)(s / denom);   // LOSS_WEIGHT = 1
    }
}

extern "C" void kernel_launch(void* const* d_in, const int* in_sizes, int n_in,
                              void* d_out, int out_size, void* d_ws, size_t ws_size,
                              hipStream_t stream) {
    const float* pred_iou   = (const float*)d_in[0];
    const float* pred_boxes = (const float*)d_in[1];
    const float* gt_boxes   = (const float*)d_in[2];
    const int*   mask       = (const int*)d_in[3];
    float* out = (float*)d_out;
    double* acc = (double*)d_ws;

    int N = in_sizes[0];
    int blocks = (N + 511) / 512;   // 2 elements per thread

    iou3d_init<<<1, 64, 0, stream>>>(acc);
    iou3d_main<<<blocks, 256, 0, stream>>>(pred_iou, pred_boxes, gt_boxes, mask, acc, N);
    iou3d_final<<<1, 64, 0, stream>>>(acc, out);
}